// Round 5
// baseline (183.847 us; speedup 1.0000x reference)
//
#include <hip/hip_runtime.h>
#include <hip/hip_cooperative_groups.h>

namespace cg = cooperative_groups;

#define EPS 1e-8f

// ---------------------------------------------------------------------------
// Fused single-dispatch chunked scan (cooperative launch, one grid sync).
// Thread (bf, c): bf = chain (b*F+f), c = time chunk of length L.
// Phase A: zero-carry local scan of chunk c -> aggregate S[c][bf].
//          (consecutive threads = consecutive bf -> wave-coalesced)
// grid.sync()
// Phase B: Horner-reconstruct exact carry-in from s0 + S[0..c), rescan the
//          chunk (L3-hot after phase A) and write normalized output.
// Arithmetic identical to the verified 2-kernel version (R4, absmax 0.0078).
// ---------------------------------------------------------------------------
template <int L>
__global__ __launch_bounds__(256, 6)   // >=6 blocks/CU so 1285 blocks co-reside
void fns5_fused(const float* __restrict__ mag,
                const float* __restrict__ s0,
                const float* __restrict__ weights,
                const float* __restrict__ bias,
                const float* __restrict__ alpha,
                float* __restrict__ out,
                float* __restrict__ S,   // [C][BF]
                int B, int T, int F, int C) {
    const int BF = B * F;
    const int g  = blockIdx.x * blockDim.x + threadIdx.x;
    const bool valid = g < BF * C;
    const int bf = valid ? g % BF : 0;
    const int c  = valid ? g / BF : 0;
    const int b  = bf / F;
    const int f  = bf - b * F;

    const float a   = 1.0f / (1.0f + expf(-alpha[f]));
    const float oma = 1.0f - a;

    const float* p = mag + ((size_t)b * T + (size_t)c * L) * F + f;

    // ---- phase A: zero-carry local scan, store chunk aggregate ----
    float local = 0.0f;
#pragma unroll
    for (int t = 0; t < L; ++t) {
        float m = valid ? p[(size_t)t * F] : 0.0f;
        local = local * oma + (m * m) * a;   // exact reference recurrence form
    }
    if (valid)
        S[(size_t)c * BF + bf] = local;

    cg::this_grid().sync();

    // ---- phase B: exact carry-in via Horner over preceding aggregates ----
    float carry = valid ? s0[bf] : 0.0f;
    if (c > 0) {
        float D = 1.0f;                       // (1-a)^L via product (ulp-equiv)
#pragma unroll
        for (int i = 0; i < L; ++i) D *= oma;
        for (int j = 0; j < c; ++j)
            carry = carry * D + S[(size_t)j * BF + bf];
    }

    const float w  = weights[f];
    const float bi = bias[f];
    float* o = out + ((size_t)b * T + (size_t)c * L) * F + f;

#pragma unroll
    for (int t = 0; t < L; ++t) {
        float m = valid ? p[(size_t)t * F] : 0.0f;
        carry = carry * oma + (m * m) * a;
        float r = m / (sqrtf(carry) + EPS) * w + bi;
        if (valid) o[(size_t)t * F] = r;
    }
}

// ---------------------------------------------------------------------------
// Proven 2-kernel path (R4) as fallback if cooperative launch is unavailable.
// ---------------------------------------------------------------------------
template <int L>
__global__ __launch_bounds__(256)
void fns4_aggregate(const float* __restrict__ mag,
                    const float* __restrict__ alpha,
                    float* __restrict__ S,
                    int B, int T, int F, int C) {
    const int BF = B * F;
    int g = blockIdx.x * blockDim.x + threadIdx.x;
    if (g >= BF * C) return;
    const int bf = g % BF;
    const int c  = g / BF;
    const int b  = bf / F;
    const int f  = bf - b * F;

    const float a   = 1.0f / (1.0f + expf(-alpha[f]));
    const float oma = 1.0f - a;
    const float* p = mag + ((size_t)b * T + (size_t)c * L) * F + f;

    float local = 0.0f;
#pragma unroll
    for (int t = 0; t < L; ++t) {
        float m = p[(size_t)t * F];
        local = local * oma + (m * m) * a;
    }
    S[(size_t)c * BF + bf] = local;
}

template <int L>
__global__ __launch_bounds__(256)
void fns4_emit(const float* __restrict__ mag,
               const float* __restrict__ s0,
               const float* __restrict__ weights,
               const float* __restrict__ bias,
               const float* __restrict__ alpha,
               const float* __restrict__ S,
               float* __restrict__ out,
               int B, int T, int F, int C) {
    const int BF = B * F;
    int g = blockIdx.x * blockDim.x + threadIdx.x;
    if (g >= BF * C) return;
    const int bf = g % BF;
    const int c  = g / BF;
    const int b  = bf / F;
    const int f  = bf - b * F;

    const float a   = 1.0f / (1.0f + expf(-alpha[f]));
    const float oma = 1.0f - a;
    const float w   = weights[f];
    const float bi  = bias[f];

    float carry = s0[bf];
    if (c > 0) {
        float D = 1.0f;
#pragma unroll
        for (int i = 0; i < L; ++i) D *= oma;
        for (int j = 0; j < c; ++j)
            carry = carry * D + S[(size_t)j * BF + bf];
    }

    const float* p = mag + ((size_t)b * T + (size_t)c * L) * F + f;
    float*       o = out + ((size_t)b * T + (size_t)c * L) * F + f;

#pragma unroll
    for (int t = 0; t < L; ++t) {
        float m = p[(size_t)t * F];
        carry = carry * oma + (m * m) * a;
        o[(size_t)t * F] = m / (sqrtf(carry) + EPS) * w + bi;
    }
}

__global__ void fns_fallback(const float* __restrict__ mag,
                             const float* __restrict__ s0,
                             const float* __restrict__ weights,
                             const float* __restrict__ bias,
                             const float* __restrict__ alpha,
                             float* __restrict__ out,
                             int B, int T, int F) {
    int bf = blockIdx.x * blockDim.x + threadIdx.x;
    int BF = B * F;
    if (bf >= BF) return;
    int b = bf / F;
    int f = bf - b * F;

    float a  = 1.0f / (1.0f + expf(-alpha[f]));
    float w  = weights[f];
    float bi = bias[f];

    float carry = s0[bf];
    const float* p = mag + (size_t)b * T * F + f;
    float*       o = out + (size_t)b * T * F + f;

    for (int t = 0; t < T; ++t) {
        float m = p[(size_t)t * F];
        carry = carry * (1.0f - a) + (m * m) * a;
        o[(size_t)t * F] = m / (sqrtf(carry) + EPS) * w + bi;
    }
}

extern "C" void kernel_launch(void* const* d_in, const int* in_sizes, int n_in,
                              void* d_out, int out_size, void* d_ws, size_t ws_size,
                              hipStream_t stream) {
    const float* mag     = (const float*)d_in[0];
    const float* s0      = (const float*)d_in[1];
    const float* weights = (const float*)d_in[2];
    const float* bias    = (const float*)d_in[3];
    const float* alpha   = (const float*)d_in[4];
    float* out = (float*)d_out;

    int F  = in_sizes[4];          // alpha is [1, F]
    int BF = in_sizes[1];          // s is [B, F]
    int B  = BF / F;
    int T  = in_sizes[0] / BF;     // mag is [B, T, F]

    constexpr int L = 50;
    if (T % L == 0) {
        int C = T / L;             // 20
        size_t need = (size_t)C * BF * sizeof(float);
        if (ws_size >= need) {
            float* S = (float*)d_ws;
            int total  = BF * C;                    // 328,960
            int blocks = (total + 255) / 256;       // 1285

            // --- try fused cooperative single dispatch ---
            void* args[] = {(void*)&mag, (void*)&s0, (void*)&weights,
                            (void*)&bias, (void*)&alpha, (void*)&out,
                            (void*)&S, (void*)&B, (void*)&T, (void*)&F,
                            (void*)&C};
            hipError_t e = hipLaunchCooperativeKernel(
                (void*)fns5_fused<L>, dim3(blocks), dim3(256),
                args, 0, stream);
            if (e == hipSuccess) return;

            // --- fallback: proven 2-kernel path ---
            fns4_aggregate<L><<<blocks, 256, 0, stream>>>(
                mag, alpha, S, B, T, F, C);
            fns4_emit<L><<<blocks, 256, 0, stream>>>(
                mag, s0, weights, bias, alpha, S, out, B, T, F, C);
            return;
        }
    }

    int threads = 256;
    int blocks  = (BF + threads - 1) / threads;
    fns_fallback<<<blocks, threads, 0, stream>>>(mag, s0, weights, bias,
                                                 alpha, out, B, T, F);
}

// Round 6
// 49.800 us; speedup vs baseline: 3.6917x; 3.6917x over previous
//
#include <hip/hip_runtime.h>

#define EPS 1e-8f

// ---------------------------------------------------------------------------
// Two-kernel chunked scan (proven R4 structure + micro-opts).
// Chains (b,f) as bf in [0,BF); time split into C chunks of L.
// Thread (bf, c) owns chunk c of chain bf; consecutive threads = consecutive
// bf -> wave-coalesced 256 B/instr; a block walks a ~51 KB contiguous window.
// k1: zero-carry local scan -> chunk aggregate S[c][bf]   (chunks 0..C-2;
//     S[C-1] is never consumed).
// k2: Horner-reconstruct exact carry-in from s0 + S[0..c), rescan (mag is
//     L3-hot from k1), normalize, non-temporal store (don't evict L3).
// ---------------------------------------------------------------------------

template <int L>
__global__ __launch_bounds__(256)
void fns6_aggregate(const float* __restrict__ mag,
                    const float* __restrict__ alpha,
                    float* __restrict__ S,   // [C-1][BF]
                    int B, int T, int F, int C1) {  // C1 = C-1
    const int BF = B * F;
    int g = blockIdx.x * blockDim.x + threadIdx.x;
    if (g >= BF * C1) return;
    const int bf = g % BF;
    const int c  = g / BF;
    const int b  = bf / F;
    const int f  = bf - b * F;

    const float a   = 1.0f / (1.0f + expf(-alpha[f]));
    const float oma = 1.0f - a;

    const float* p = mag + ((size_t)b * T + (size_t)c * L) * F + f;

    float local = 0.0f;
#pragma unroll 10
    for (int t = 0; t < L; ++t) {
        float m = p[(size_t)t * F];
        local = local * oma + (m * m) * a;   // exact reference recurrence form
    }
    S[(size_t)c * BF + bf] = local;
}

template <int L>
__global__ __launch_bounds__(256)
void fns6_emit(const float* __restrict__ mag,
               const float* __restrict__ s0,
               const float* __restrict__ weights,
               const float* __restrict__ bias,
               const float* __restrict__ alpha,
               const float* __restrict__ S,   // [C-1][BF]
               float* __restrict__ out,
               int B, int T, int F, int C) {
    const int BF = B * F;
    int g = blockIdx.x * blockDim.x + threadIdx.x;
    if (g >= BF * C) return;
    const int bf = g % BF;
    const int c  = g / BF;
    const int b  = bf / F;
    const int f  = bf - b * F;

    const float a   = 1.0f / (1.0f + expf(-alpha[f]));
    const float oma = 1.0f - a;
    const float w   = weights[f];
    const float bi  = bias[f];

    // exact carry-in for chunk c (Horner over preceding chunk aggregates;
    // identical arithmetic to a sequential middle pass)
    float carry = s0[bf];
    if (c > 0) {
        float D = 1.0f;                      // (1-a)^L via product
#pragma unroll
        for (int i = 0; i < L; ++i) D *= oma;
        for (int j = 0; j < c; ++j)
            carry = carry * D + S[(size_t)j * BF + bf];
    }

    const float* p = mag + ((size_t)b * T + (size_t)c * L) * F + f;
    float*       o = out + ((size_t)b * T + (size_t)c * L) * F + f;

#pragma unroll 10
    for (int t = 0; t < L; ++t) {
        float m = p[(size_t)t * F];
        carry = carry * oma + (m * m) * a;
        // 1/(sqrt+eps) via hw rcp (~1 ulp); output bounded by ~w/sqrt(a) so
        // abs error ~1e-6 -- far under threshold. Handles m=0 (-> 0) safely.
        float r = __builtin_amdgcn_rcpf(sqrtf(carry) + EPS);
        float v = m * r * w + bi;
        __builtin_nontemporal_store(v, o + (size_t)t * F);  // keep mag in L3
    }
}

// ---------------------------------------------------------------------------
// Fallback: one thread per (b,f) chain (general shapes / tiny workspace).
// ---------------------------------------------------------------------------
__global__ void fns_fallback(const float* __restrict__ mag,
                             const float* __restrict__ s0,
                             const float* __restrict__ weights,
                             const float* __restrict__ bias,
                             const float* __restrict__ alpha,
                             float* __restrict__ out,
                             int B, int T, int F) {
    int bf = blockIdx.x * blockDim.x + threadIdx.x;
    int BF = B * F;
    if (bf >= BF) return;
    int b = bf / F;
    int f = bf - b * F;

    float a  = 1.0f / (1.0f + expf(-alpha[f]));
    float w  = weights[f];
    float bi = bias[f];

    float carry = s0[bf];
    const float* p = mag + (size_t)b * T * F + f;
    float*       o = out + (size_t)b * T * F + f;

    for (int t = 0; t < T; ++t) {
        float m = p[(size_t)t * F];
        carry = carry * (1.0f - a) + (m * m) * a;
        o[(size_t)t * F] = m / (sqrtf(carry) + EPS) * w + bi;
    }
}

extern "C" void kernel_launch(void* const* d_in, const int* in_sizes, int n_in,
                              void* d_out, int out_size, void* d_ws, size_t ws_size,
                              hipStream_t stream) {
    const float* mag     = (const float*)d_in[0];
    const float* s0      = (const float*)d_in[1];
    const float* weights = (const float*)d_in[2];
    const float* bias    = (const float*)d_in[3];
    const float* alpha   = (const float*)d_in[4];
    float* out = (float*)d_out;

    int F  = in_sizes[4];          // alpha is [1, F]
    int BF = in_sizes[1];          // s is [B, F]
    int B  = BF / F;
    int T  = in_sizes[0] / BF;     // mag is [B, T, F]

    constexpr int L = 50;          // compile-time chunk length
    if (T % L == 0) {
        int C  = T / L;            // 20 for T=1000
        int C1 = C - 1;
        size_t need = (size_t)C1 * BF * sizeof(float);
        if (C1 >= 1 && ws_size >= need) {
            float* S = (float*)d_ws;

            int n1 = BF * C1;                    // 312,512
            int n2 = BF * C;                     // 328,960
            fns6_aggregate<L><<<(n1 + 255) / 256, 256, 0, stream>>>(
                mag, alpha, S, B, T, F, C1);
            fns6_emit<L><<<(n2 + 255) / 256, 256, 0, stream>>>(
                mag, s0, weights, bias, alpha, S, out, B, T, F, C);
            return;
        }
    }

    int threads = 256;
    int blocks  = (BF + threads - 1) / threads;
    fns_fallback<<<blocks, threads, 0, stream>>>(mag, s0, weights, bias,
                                                 alpha, out, B, T, F);
}